// Round 1
// baseline (133.150 us; speedup 1.0000x reference)
//
#include <hip/hip_runtime.h>
#include <stdint.h>

#define NUM_ACT 6
#define NUM_OPP 3
#define NUM_SAMPLE 80
#define BATCH 4096
#define DIM 512
#define ENT_IDX 98304   /* BATCH*6 + 3*BATCH*6 */

// ---------------- JAX threefry2x32 (key = (0, 42)) ----------------
__device__ __forceinline__ uint32_t rotl32(uint32_t x, int d) {
  return (x << d) | (x >> (32 - d));
}

__device__ __forceinline__ void tf_round4(uint32_t& x0, uint32_t& x1,
                                          int r0, int r1, int r2, int r3) {
  x0 += x1; x1 = rotl32(x1, r0); x1 ^= x0;
  x0 += x1; x1 = rotl32(x1, r1); x1 ^= x0;
  x0 += x1; x1 = rotl32(x1, r2); x1 ^= x0;
  x0 += x1; x1 = rotl32(x1, r3); x1 ^= x0;
}

__device__ __forceinline__ void threefry2x32(uint32_t k0, uint32_t k1,
                                             uint32_t& x0, uint32_t& x1) {
  const uint32_t ks2 = k0 ^ k1 ^ 0x1BD11BDAu;
  x0 += k0;  x1 += k1;
  tf_round4(x0, x1, 13, 15, 26, 6);  x0 += k1;  x1 += ks2 + 1u;
  tf_round4(x0, x1, 17, 29, 16, 24); x0 += ks2; x1 += k0  + 2u;
  tf_round4(x0, x1, 13, 15, 26, 6);  x0 += k0;  x1 += k1  + 3u;
  tf_round4(x0, x1, 17, 29, 16, 24); x0 += k1;  x1 += ks2 + 4u;
  tf_round4(x0, x1, 13, 15, 26, 6);  x0 += ks2; x1 += k0  + 5u;
}

__device__ __forceinline__ float jax_uniform(uint32_t flat_idx) {
  uint32_t x0 = 0u, x1 = flat_idx;
  threefry2x32(0u, 42u, x0, x1);
  uint32_t bits = x0 ^ x1;
  return __uint_as_float((bits >> 9) | 0x3f800000u) - 1.0f;   // [0,1)
}

// ---------------- Single fused kernel: one block per batch row ----------------
// GEMV (24 dots of len 512) + opponent softmax + entropy atomics + dist write
// + categorical sampling + agent softmax tail, all in-block. No split-K, no
// inter-kernel round-trips. Logit contraction order matches the verified
// k1+k2 exactly (bias first, then chunks g=0..7, sequential fmaf within
// chunk) so dist bits — and therefore sampling decisions — are unchanged.
__global__ __launch_bounds__(256) void k_fused(
    const float* __restrict__ x, const float* __restrict__ Wopp,
    const float* __restrict__ bopp, const float* __restrict__ W,
    const float* __restrict__ bias, float* __restrict__ out) {
  const int b = blockIdx.x;
  const int t = threadIdx.x;

  __shared__ float xs[DIM];
  __shared__ float s_part[8][24];
  __shared__ float s_dist[NUM_OPP][NUM_ACT];
  __shared__ float s_xw[NUM_ACT];
  __shared__ float s_W2[NUM_OPP * NUM_ACT][NUM_ACT];
  __shared__ int   s_act[NUM_OPP][NUM_SAMPLE];
  __shared__ float s_prob[NUM_OPP][NUM_SAMPLE];

  // ---- Phase A: stage x row (coalesced float2/thread) + tail weights ----
  {
    float2 v = *(const float2*)(x + (size_t)b * DIM + t * 2);
    *(float2*)(xs + t * 2) = v;
  }
  if (t >= 128 && t < 128 + 108) {
    int i = t - 128;
    s_W2[i / 6][i % 6] = W[DIM * NUM_ACT + i];
  }
  __syncthreads();

  // ---- Phase B: GEMV partials. 192 threads: c = t%24 col, g = t/24 chunk ----
  // Weights are 48 KB total -> L1/L2 resident across all 4096 blocks.
  if (t < 192) {
    const int c = t % 24, g = t / 24;
    const float* wp = (c < 18) ? (Wopp + (c / 6) * (DIM * NUM_ACT) + (c % 6))
                               : (W + (c - 18));
    wp += (size_t)(g * 64) * NUM_ACT;
    const float* xp = xs + g * 64;
    float acc = 0.f;
#pragma unroll 8
    for (int d = 0; d < 64; d++)
      acc = fmaf(xp[d], wp[d * NUM_ACT], acc);   // serial fmaf chain: order fixed
    s_part[g][c] = acc;
  }
  __syncthreads();

  // ---- Phase C: softmax per opponent (t=0..2), xw+bias (t=18..23) ----
  if (t < NUM_OPP) {
    const int k = t;
    float l[NUM_ACT];
#pragma unroll
    for (int a = 0; a < NUM_ACT; a++) {
      float s = bopp[k * NUM_ACT + a];          // bias first (matches old k2)
#pragma unroll
      for (int g = 0; g < 8; g++) s += s_part[g][k * NUM_ACT + a];
      l[a] = s;
    }
    float m = l[0];
#pragma unroll
    for (int a = 1; a < NUM_ACT; a++) m = fmaxf(m, l[a]);
    float e[NUM_ACT], Z = 0.f;
#pragma unroll
    for (int a = 0; a < NUM_ACT; a++) { e[a] = expf(l[a] - m); Z += e[a]; }
    float logZ = logf(Z);
    float H = 0.f;
#pragma unroll
    for (int a = 0; a < NUM_ACT; a++) {
      float pa = e[a] / Z;
      s_dist[k][a] = pa;
      out[BATCH * NUM_ACT + ((size_t)k * BATCH + b) * NUM_ACT + a] = pa;
      H -= pa * ((l[a] - m) - logZ);
    }
    // entropy: pre-scaled per-row contribution straight into the output slot
    atomicAdd(out + ENT_IDX, H * (1.0f / 12288.0f));
  } else if (t >= 18 && t < 24) {
    const int a = t - 18;
    float s = bias[a];                           // bias first (matches old k3)
#pragma unroll
    for (int g = 0; g < 8; g++) s += s_part[g][18 + a];
    s_xw[a] = s;
  }
  __syncthreads();

  // ---- Phase D: inverse-CDF sampling, 1 threefry per (opponent, sample) ----
  if (t < NUM_OPP * NUM_SAMPLE) {
    const int k = t / NUM_SAMPLE, s = t - k * NUM_SAMPLE;
    float u = jax_uniform((uint32_t)(k * NUM_SAMPLE + s) * BATCH + (uint32_t)b);
    float c = s_dist[k][0], pr = s_dist[k][0];
    int sel = 0;
#pragma unroll
    for (int a = 1; a < NUM_ACT; a++) {
      bool take = (u >= c);
      sel += take ? 1 : 0;
      pr = take ? s_dist[k][a] : pr;
      c += s_dist[k][a];
    }
    s_act[k][s] = sel;
    s_prob[k][s] = pr;
  }
  __syncthreads();

  // ---- Phase E: tail, wave 0 only, shuffle reductions ----
  if (t < 64) {
    float p1a = s_prob[0][t] * s_prob[1][t] * s_prob[2][t];
    const bool hasb = t < (NUM_SAMPLE - 64);
    float p1b = 0.f;
    if (hasb) p1b = s_prob[0][t + 64] * s_prob[1][t + 64] * s_prob[2][t + 64];
    float tot = p1a + p1b;
#pragma unroll
    for (int m = 32; m > 0; m >>= 1) tot += __shfl_xor(tot, m);

    float o[NUM_ACT];
#pragma unroll
    for (int a = 0; a < NUM_ACT; a++) o[a] = 0.f;
    {
      int a0 = s_act[0][t], a1 = s_act[1][t], a2 = s_act[2][t];
      float la[NUM_ACT];
#pragma unroll
      for (int a = 0; a < NUM_ACT; a++)
        la[a] = s_xw[a] + s_W2[a0][a] + s_W2[6 + a1][a] + s_W2[12 + a2][a];
      float m = la[0];
#pragma unroll
      for (int a = 1; a < NUM_ACT; a++) m = fmaxf(m, la[a]);
      float e[NUM_ACT], Z = 0.f;
#pragma unroll
      for (int a = 0; a < NUM_ACT; a++) { e[a] = expf(la[a] - m); Z += e[a]; }
      float wz = (p1a / tot) / Z;
#pragma unroll
      for (int a = 0; a < NUM_ACT; a++) o[a] = wz * e[a];
    }
    if (hasb) {
      int j = t + 64;
      int a0 = s_act[0][j], a1 = s_act[1][j], a2 = s_act[2][j];
      float la[NUM_ACT];
#pragma unroll
      for (int a = 0; a < NUM_ACT; a++)
        la[a] = s_xw[a] + s_W2[a0][a] + s_W2[6 + a1][a] + s_W2[12 + a2][a];
      float m = la[0];
#pragma unroll
      for (int a = 1; a < NUM_ACT; a++) m = fmaxf(m, la[a]);
      float e[NUM_ACT], Z = 0.f;
#pragma unroll
      for (int a = 0; a < NUM_ACT; a++) { e[a] = expf(la[a] - m); Z += e[a]; }
      float wz = (p1b / tot) / Z;
#pragma unroll
      for (int a = 0; a < NUM_ACT; a++) o[a] += wz * e[a];
    }
#pragma unroll
    for (int m = 32; m > 0; m >>= 1)
#pragma unroll
      for (int a = 0; a < NUM_ACT; a++) o[a] += __shfl_xor(o[a], m);
    if (t == 0) {
#pragma unroll
      for (int a = 0; a < NUM_ACT; a++) out[b * NUM_ACT + a] = o[a];
    }
  }
}

extern "C" void kernel_launch(void* const* d_in, const int* in_sizes, int n_in,
                              void* d_out, int out_size, void* d_ws, size_t ws_size,
                              hipStream_t stream) {
  const float* x    = (const float*)d_in[0];
  const float* Wopp = (const float*)d_in[1];
  const float* bopp = (const float*)d_in[2];
  const float* W    = (const float*)d_in[3];
  const float* bias = (const float*)d_in[4];
  float* out = (float*)d_out;

  // zero only the 4-byte entropy accumulator (stream-ordered, graph-capturable)
  hipMemsetAsync(out + ENT_IDX, 0, sizeof(float), stream);
  k_fused<<<BATCH, 256, 0, stream>>>(x, Wopp, bopp, W, bias, out);
}

// Round 2
// 114.547 us; speedup vs baseline: 1.1624x; 1.1624x over previous
//
#include <hip/hip_runtime.h>
#include <stdint.h>

#define NUM_ACT 6
#define NUM_OPP 3
#define NUM_SAMPLE 80
#define BATCH 4096
#define DIM 512
#define ENT_IDX 98304   /* BATCH*6 + 3*BATCH*6 */

// ---------------- JAX threefry2x32 (key = (0, 42)) ----------------
__device__ __forceinline__ uint32_t rotl32(uint32_t x, int d) {
  return (x << d) | (x >> (32 - d));
}

__device__ __forceinline__ void tf_round4(uint32_t& x0, uint32_t& x1,
                                          int r0, int r1, int r2, int r3) {
  x0 += x1; x1 = rotl32(x1, r0); x1 ^= x0;
  x0 += x1; x1 = rotl32(x1, r1); x1 ^= x0;
  x0 += x1; x1 = rotl32(x1, r2); x1 ^= x0;
  x0 += x1; x1 = rotl32(x1, r3); x1 ^= x0;
}

__device__ __forceinline__ void threefry2x32(uint32_t k0, uint32_t k1,
                                             uint32_t& x0, uint32_t& x1) {
  const uint32_t ks2 = k0 ^ k1 ^ 0x1BD11BDAu;
  x0 += k0;  x1 += k1;
  tf_round4(x0, x1, 13, 15, 26, 6);  x0 += k1;  x1 += ks2 + 1u;
  tf_round4(x0, x1, 17, 29, 16, 24); x0 += ks2; x1 += k0  + 2u;
  tf_round4(x0, x1, 13, 15, 26, 6);  x0 += k0;  x1 += k1  + 3u;
  tf_round4(x0, x1, 17, 29, 16, 24); x0 += k1;  x1 += ks2 + 4u;
  tf_round4(x0, x1, 13, 15, 26, 6);  x0 += ks2; x1 += k0  + 5u;
}

__device__ __forceinline__ float jax_uniform(uint32_t flat_idx) {
  uint32_t x0 = 0u, x1 = flat_idx;
  threefry2x32(0u, 42u, x0, x1);
  uint32_t bits = x0 ^ x1;
  return __uint_as_float((bits >> 9) | 0x3f800000u) - 1.0f;   // [0,1)
}

// ---------------- Fused kernel: one block per batch row ----------------
// Same bit-exact GEMV chunk order / softmax / sampling as the verified R1
// kernel. Changes vs R1 (atomic-drain theory):
//   * NO global atomics. Per-block entropy H is shfl-gathered to lane 0
//     (no barrier) and stored to ws[b] at the very END (no barrier after
//     it -> no vmcnt-drain stall on the critical path).
//   * dist stores to `out` moved after the last barrier, done by wave 1
//     while wave 0 runs the tail -> no pre-barrier drain.
__global__ __launch_bounds__(256) void k_fused(
    const float* __restrict__ x, const float* __restrict__ Wopp,
    const float* __restrict__ bopp, const float* __restrict__ W,
    const float* __restrict__ bias, float* __restrict__ out,
    float* __restrict__ ws_H) {
  const int b = blockIdx.x;
  const int t = threadIdx.x;

  __shared__ float xs[DIM];
  __shared__ float s_part[8][24];
  __shared__ float s_dist[NUM_OPP][NUM_ACT];
  __shared__ float s_xw[NUM_ACT];
  __shared__ float s_W2[NUM_OPP * NUM_ACT][NUM_ACT];
  __shared__ int   s_act[NUM_OPP][NUM_SAMPLE];
  __shared__ float s_prob[NUM_OPP][NUM_SAMPLE];

  // ---- Phase A: stage x row (coalesced float2/thread) + tail weights ----
  {
    float2 v = *(const float2*)(x + (size_t)b * DIM + t * 2);
    *(float2*)(xs + t * 2) = v;
  }
  if (t >= 128 && t < 128 + 108) {
    int i = t - 128;
    s_W2[i / 6][i % 6] = W[DIM * NUM_ACT + i];
  }
  __syncthreads();

  // ---- Phase B: GEMV partials. 192 threads: c = t%24 col, g = t/24 chunk ----
  // Serial fmaf chain per 64-chunk: order fixed -> dist bit-identical.
  if (t < 192) {
    const int c = t % 24, g = t / 24;
    const float* wp = (c < 18) ? (Wopp + (c / 6) * (DIM * NUM_ACT) + (c % 6))
                               : (W + (c - 18));
    wp += (size_t)(g * 64) * NUM_ACT;
    const float* xp = xs + g * 64;
    float acc = 0.f;
#pragma unroll 8
    for (int d = 0; d < 64; d++)
      acc = fmaf(xp[d], wp[d * NUM_ACT], acc);
    s_part[g][c] = acc;
  }
  __syncthreads();

  // ---- Phase C: softmax per opponent (t=0..2), xw+bias (t=18..23) ----
  float H = 0.f;   // per-row entropy contribution (lanes 0..2 only)
  if (t < NUM_OPP) {
    const int k = t;
    float l[NUM_ACT];
#pragma unroll
    for (int a = 0; a < NUM_ACT; a++) {
      float s = bopp[k * NUM_ACT + a];          // bias first (matches old k2)
#pragma unroll
      for (int g = 0; g < 8; g++) s += s_part[g][k * NUM_ACT + a];
      l[a] = s;
    }
    float m = l[0];
#pragma unroll
    for (int a = 1; a < NUM_ACT; a++) m = fmaxf(m, l[a]);
    float e[NUM_ACT], Z = 0.f;
#pragma unroll
    for (int a = 0; a < NUM_ACT; a++) { e[a] = expf(l[a] - m); Z += e[a]; }
    float logZ = logf(Z);
#pragma unroll
    for (int a = 0; a < NUM_ACT; a++) {
      float pa = e[a] / Z;
      s_dist[k][a] = pa;
      H -= pa * ((l[a] - m) - logZ);
    }
  } else if (t >= 18 && t < 24) {
    const int a = t - 18;
    float s = bias[a];                           // bias first (matches old k3)
#pragma unroll
    for (int g = 0; g < 8; g++) s += s_part[g][18 + a];
    s_xw[a] = s;
  }
  // gather H0+H1+H2 into lane 0 of wave 0 (no barrier needed: same wave)
  if (t < 64) {
    H += __shfl_down(H, 1);
    H += __shfl_down(H, 2);
  }
  __syncthreads();

  // ---- Phase D: inverse-CDF sampling, 1 threefry per (opponent, sample) ----
  if (t < NUM_OPP * NUM_SAMPLE) {
    const int k = t / NUM_SAMPLE, s = t - k * NUM_SAMPLE;
    float u = jax_uniform((uint32_t)(k * NUM_SAMPLE + s) * BATCH + (uint32_t)b);
    float c = s_dist[k][0], pr = s_dist[k][0];
    int sel = 0;
#pragma unroll
    for (int a = 1; a < NUM_ACT; a++) {
      bool take = (u >= c);
      sel += take ? 1 : 0;
      pr = take ? s_dist[k][a] : pr;
      c += s_dist[k][a];
    }
    s_act[k][s] = sel;
    s_prob[k][s] = pr;
  }
  __syncthreads();

  // ---- Phase E: wave 0 tail; wave 1 writes dist (no barrier after) ----
  if (t >= 64 && t < 64 + 18) {
    int i = t - 64, k = i / 6, a = i % 6;
    out[BATCH * NUM_ACT + ((size_t)k * BATCH + b) * NUM_ACT + a] = s_dist[k][a];
  }
  if (t < 64) {
    float p1a = s_prob[0][t] * s_prob[1][t] * s_prob[2][t];
    const bool hasb = t < (NUM_SAMPLE - 64);
    float p1b = 0.f;
    if (hasb) p1b = s_prob[0][t + 64] * s_prob[1][t + 64] * s_prob[2][t + 64];
    float tot = p1a + p1b;
#pragma unroll
    for (int m = 32; m > 0; m >>= 1) tot += __shfl_xor(tot, m);

    float o[NUM_ACT];
#pragma unroll
    for (int a = 0; a < NUM_ACT; a++) o[a] = 0.f;
    {
      int a0 = s_act[0][t], a1 = s_act[1][t], a2 = s_act[2][t];
      float la[NUM_ACT];
#pragma unroll
      for (int a = 0; a < NUM_ACT; a++)
        la[a] = s_xw[a] + s_W2[a0][a] + s_W2[6 + a1][a] + s_W2[12 + a2][a];
      float m = la[0];
#pragma unroll
      for (int a = 1; a < NUM_ACT; a++) m = fmaxf(m, la[a]);
      float e[NUM_ACT], Z = 0.f;
#pragma unroll
      for (int a = 0; a < NUM_ACT; a++) { e[a] = expf(la[a] - m); Z += e[a]; }
      float wz = (p1a / tot) / Z;
#pragma unroll
      for (int a = 0; a < NUM_ACT; a++) o[a] = wz * e[a];
    }
    if (hasb) {
      int j = t + 64;
      int a0 = s_act[0][j], a1 = s_act[1][j], a2 = s_act[2][j];
      float la[NUM_ACT];
#pragma unroll
      for (int a = 0; a < NUM_ACT; a++)
        la[a] = s_xw[a] + s_W2[a0][a] + s_W2[6 + a1][a] + s_W2[12 + a2][a];
      float m = la[0];
#pragma unroll
      for (int a = 1; a < NUM_ACT; a++) m = fmaxf(m, la[a]);
      float e[NUM_ACT], Z = 0.f;
#pragma unroll
      for (int a = 0; a < NUM_ACT; a++) { e[a] = expf(la[a] - m); Z += e[a]; }
      float wz = (p1b / tot) / Z;
#pragma unroll
      for (int a = 0; a < NUM_ACT; a++) o[a] += wz * e[a];
    }
#pragma unroll
    for (int m = 32; m > 0; m >>= 1)
#pragma unroll
      for (int a = 0; a < NUM_ACT; a++) o[a] += __shfl_xor(o[a], m);
    if (t == 0) {
#pragma unroll
      for (int a = 0; a < NUM_ACT; a++) out[b * NUM_ACT + a] = o[a];
      ws_H[b] = H;   // fire-and-forget: no barrier follows
    }
  }
}

// ---------------- Entropy reduce: 4096 floats -> 1 scalar ----------------
__global__ __launch_bounds__(256) void k_ent(const float* __restrict__ ws_H,
                                             float* __restrict__ out) {
  const int t = threadIdx.x;
  const float4* p = (const float4*)ws_H;   // 1024 float4
  float s = 0.f;
#pragma unroll
  for (int i = 0; i < 4; i++) {
    float4 v = p[t + 256 * i];             // coalesced
    s += v.x + v.y + v.z + v.w;
  }
#pragma unroll
  for (int m = 32; m > 0; m >>= 1) s += __shfl_xor(s, m);
  __shared__ float sw[4];
  if ((t & 63) == 0) sw[t >> 6] = s;
  __syncthreads();
  if (t == 0)
    out[ENT_IDX] = (sw[0] + sw[1] + sw[2] + sw[3]) * (1.0f / 12288.0f);
}

extern "C" void kernel_launch(void* const* d_in, const int* in_sizes, int n_in,
                              void* d_out, int out_size, void* d_ws, size_t ws_size,
                              hipStream_t stream) {
  const float* x    = (const float*)d_in[0];
  const float* Wopp = (const float*)d_in[1];
  const float* bopp = (const float*)d_in[2];
  const float* W    = (const float*)d_in[3];
  const float* bias = (const float*)d_in[4];
  float* out = (float*)d_out;
  float* ws_H = (float*)d_ws;              // 4096 floats = 16 KB

  k_fused<<<BATCH, 256, 0, stream>>>(x, Wopp, bopp, W, bias, out, ws_H);
  k_ent<<<1, 256, 0, stream>>>(ws_H, out);
}

// Round 3
// 86.694 us; speedup vs baseline: 1.5359x; 1.3213x over previous
//
#include <hip/hip_runtime.h>
#include <stdint.h>

#define NUM_ACT 6
#define NUM_OPP 3
#define NUM_SAMPLE 80
#define BATCH 4096
#define DIM 512
#define ACC_STRIDE 98304   /* BATCH*24 */
#define TROWS 32
#define ENT_IDX 98304      /* BATCH*6 + 3*BATCH*6 */

// ---------------- JAX threefry2x32 (key = (0, 42)) ----------------
__device__ __forceinline__ uint32_t rotl32(uint32_t x, int d) {
  return (x << d) | (x >> (32 - d));
}

__device__ __forceinline__ void tf_round4(uint32_t& x0, uint32_t& x1,
                                          int r0, int r1, int r2, int r3) {
  x0 += x1; x1 = rotl32(x1, r0); x1 ^= x0;
  x0 += x1; x1 = rotl32(x1, r1); x1 ^= x0;
  x0 += x1; x1 = rotl32(x1, r2); x1 ^= x0;
  x0 += x1; x1 = rotl32(x1, r3); x1 ^= x0;
}

__device__ __forceinline__ void threefry2x32(uint32_t k0, uint32_t k1,
                                             uint32_t& x0, uint32_t& x1) {
  const uint32_t ks2 = k0 ^ k1 ^ 0x1BD11BDAu;
  x0 += k0;  x1 += k1;
  tf_round4(x0, x1, 13, 15, 26, 6);  x0 += k1;  x1 += ks2 + 1u;
  tf_round4(x0, x1, 17, 29, 16, 24); x0 += ks2; x1 += k0  + 2u;
  tf_round4(x0, x1, 13, 15, 26, 6);  x0 += k0;  x1 += k1  + 3u;
  tf_round4(x0, x1, 17, 29, 16, 24); x0 += k1;  x1 += ks2 + 4u;
  tf_round4(x0, x1, 13, 15, 26, 6);  x0 += ks2; x1 += k0  + 5u;
}

__device__ __forceinline__ float jax_uniform(uint32_t flat_idx) {
  uint32_t x0 = 0u, x1 = flat_idx;
  threefry2x32(0u, 42u, x0, x1);
  uint32_t bits = x0 ^ x1;
  return __uint_as_float((bits >> 9) | 0x3f800000u) - 1.0f;   // [0,1)
}

__device__ __forceinline__ void dot4(float& a, float4 u, float4 v) {
  a = fmaf(u.x, v.x, a); a = fmaf(u.y, v.y, a);
  a = fmaf(u.z, v.z, a); a = fmaf(u.w, v.w, a);
}

// ---------------- K1: split-K tiled GEMM -> per-chunk partials ----------------
// VERBATIM from the verified R0 kernel (defines logit bit patterns).
template<int NCH>
__global__ __launch_bounds__(128) void k1_gemm(
    const float* __restrict__ x, const float* __restrict__ Wopp,
    const float* __restrict__ W, float* __restrict__ part) {
  constexpr int WIDTH = 512 / NCH;
  constexpr int XSTR = WIDTH + 4;
  const int tile = blockIdx.x / NCH;
  const int ch = blockIdx.x % NCH;
  const int rowbase = tile * TROWS;
  const int dbase = ch * WIDTH;
  __shared__ float xs[TROWS * XSTR];
  __shared__ float wt[24 * XSTR];
  const int t = threadIdx.x;

  for (int f = t; f < TROWS * (WIDTH / 4); f += 128) {
    int row = f / (WIDTH / 4), c4 = (f % (WIDTH / 4)) << 2;
    float4 v = *(const float4*)(x + (size_t)(rowbase + row) * DIM + dbase + c4);
    *(float4*)(xs + row * XSTR + c4) = v;
  }
  for (int i = t; i < 24 * WIDTH; i += 128) {
    int c = i % 24, dd = i / 24;
    int d = dbase + dd;
    float v = (c < 18) ? Wopp[(c / 6) * (DIM * 6) + d * 6 + (c % 6)]
                       : W[d * 6 + (c - 18)];
    wt[c * XSTR + dd] = v;
  }
  __syncthreads();

  const int rowg = t >> 3, colg = t & 7;
  float acc[2][3] = {{0.f, 0.f, 0.f}, {0.f, 0.f, 0.f}};
  const float* xp = xs + (rowg * 2) * XSTR;
  const float* wp = wt + (colg * 3) * XSTR;
#pragma unroll 4
  for (int dd = 0; dd < WIDTH; dd += 4) {
    float4 x0 = *(const float4*)(xp + dd);
    float4 x1 = *(const float4*)(xp + XSTR + dd);
    float4 w0 = *(const float4*)(wp + dd);
    float4 w1 = *(const float4*)(wp + XSTR + dd);
    float4 w2 = *(const float4*)(wp + 2 * XSTR + dd);
    dot4(acc[0][0], x0, w0); dot4(acc[0][1], x0, w1); dot4(acc[0][2], x0, w2);
    dot4(acc[1][0], x1, w0); dot4(acc[1][1], x1, w1); dot4(acc[1][2], x1, w2);
  }
  const int r0 = rowbase + rowg * 2, c0 = colg * 3;
  float* p = part + (size_t)ch * ACC_STRIDE;
#pragma unroll
  for (int rr = 0; rr < 2; rr++)
#pragma unroll
    for (int cc = 0; cc < 3; cc++)
      p[(r0 + rr) * 24 + c0 + cc] = acc[rr][cc];
}

// ---------------- K3f: wave-per-row tail, ZERO barriers ----------------
// One wave = one row. Per-wave private LDS strip (in-wave DS ordering, no
// __syncthreads). All arithmetic sequences copied bit-for-bit from the
// verified R2 kernel; only the hash->lane assignment differs (redistributed
// by shuffles, values unchanged).
#define WSTR 144   /* per-wave LDS floats: [0,108) W2, [112,130) dist, [136,142) xw */

template<int NCH>
__global__ __launch_bounds__(256) void k3f(
    const float* __restrict__ part, const float* __restrict__ bopp,
    const float* __restrict__ W, const float* __restrict__ bias,
    float* __restrict__ out, float* __restrict__ ws_H) {
  const int w = threadIdx.x >> 6;
  const int l = threadIdx.x & 63;
  const int b = blockIdx.x * 4 + w;
  __shared__ float lds[4][WSTR];
  float* L = lds[w];

  // stage tail weights W2 (108 floats) into this wave's private strip
  if (l < 54) {
    float2 v = *(const float2*)(W + DIM * NUM_ACT + 2 * l);
    L[2 * l] = v.x; L[2 * l + 1] = v.y;
  }

  // logits -> softmax (lanes 0..2) / xw (lanes 18..23); same fp sequence as R2
  float H = 0.f;
  if (l < NUM_OPP) {
    const int k = l;
    float lg[NUM_ACT];
#pragma unroll
    for (int a = 0; a < NUM_ACT; a++) {
      float s = bopp[k * NUM_ACT + a];                  // bias first
#pragma unroll
      for (int g = 0; g < NCH; g++)
        s += part[g * ACC_STRIDE + b * 24 + k * NUM_ACT + a];
      lg[a] = s;
    }
    float m = lg[0];
#pragma unroll
    for (int a = 1; a < NUM_ACT; a++) m = fmaxf(m, lg[a]);
    float e[NUM_ACT], Z = 0.f;
#pragma unroll
    for (int a = 0; a < NUM_ACT; a++) { e[a] = expf(lg[a] - m); Z += e[a]; }
    float logZ = logf(Z);
#pragma unroll
    for (int a = 0; a < NUM_ACT; a++) {
      float pa = e[a] / Z;
      L[112 + k * NUM_ACT + a] = pa;
      H -= pa * ((lg[a] - m) - logZ);
    }
  } else if (l >= 18 && l < 24) {
    const int a = l - 18;
    float s = bias[a];                                   // bias first
#pragma unroll
    for (int g = 0; g < NCH; g++)
      s += part[g * ACC_STRIDE + b * 24 + 18 + a];
    L[136 + a] = s;
  }
  // gather H0+H1+H2 -> lane 0 (identical shfl sequence to R2)
  H += __shfl_down(H, 1);
  H += __shfl_down(H, 2);

  // broadcast dist into registers (in-wave DS ordering guarantees the writes
  // above have landed before these reads retire; no barrier needed)
  float d[18];
#pragma unroll
  for (int i = 0; i < 18; i++) d[i] = L[112 + i];

  // ---- sampling: a-half (s = l) for k=0,1,2 on every lane ----
  int   act_a[3];
  float pr_a[3];
#pragma unroll
  for (int k = 0; k < NUM_OPP; k++) {
    float u = jax_uniform((uint32_t)(k * NUM_SAMPLE + l) * BATCH + (uint32_t)b);
    float c = d[k * 6 + 0], pr = d[k * 6 + 0];
    int sel = 0;
#pragma unroll
    for (int a = 1; a < NUM_ACT; a++) {
      bool take = (u >= c);
      sel += take ? 1 : 0;
      pr = take ? d[k * 6 + a] : pr;
      c += d[k * 6 + a];
    }
    act_a[k] = sel; pr_a[k] = pr;
  }
  // ---- b-half (s = 64 + l%16) computed on lanes 0..47, k = l/16 ----
  float prb = 0.f; int actb = 0;
  if (l < 48) {
    const int k = l >> 4, s = 64 + (l & 15);
    float u = jax_uniform((uint32_t)(k * NUM_SAMPLE + s) * BATCH + (uint32_t)b);
    // dist via lane-varying LDS reads (k runtime -> avoid VGPR dyn-index)
    float c = L[112 + k * 6 + 0], pr = c;
    int sel = 0;
#pragma unroll
    for (int a = 1; a < NUM_ACT; a++) {
      float da = L[112 + k * 6 + a];
      bool take = (u >= c);
      sel += take ? 1 : 0;
      pr = take ? da : pr;
      c += da;
    }
    actb = sel; prb = pr;
  }
  // redistribute b-half to lanes 0..15 (same sample->lane map as R2: j=t+64)
  const int tm = l & 15;
  float pb0 = __shfl(prb, tm), pb1 = __shfl(prb, tm + 16), pb2 = __shfl(prb, tm + 32);
  int   ab0 = __shfl(actb, tm), ab1 = __shfl(actb, tm + 16), ab2 = __shfl(actb, tm + 32);

  const bool hasb = l < (NUM_SAMPLE - 64);
  float p1a = pr_a[0] * pr_a[1] * pr_a[2];
  float p1b = 0.f;
  if (hasb) p1b = pb0 * pb1 * pb2;
  float tot = p1a + p1b;
#pragma unroll
  for (int m = 32; m > 0; m >>= 1) tot += __shfl_xor(tot, m);

  float xw[NUM_ACT];
#pragma unroll
  for (int a = 0; a < NUM_ACT; a++) xw[a] = L[136 + a];

  float o[NUM_ACT];
#pragma unroll
  for (int a = 0; a < NUM_ACT; a++) o[a] = 0.f;
  {
    int a0 = act_a[0], a1 = act_a[1], a2 = act_a[2];
    float la[NUM_ACT];
#pragma unroll
    for (int a = 0; a < NUM_ACT; a++)
      la[a] = xw[a] + L[a0 * 6 + a] + L[(6 + a1) * 6 + a] + L[(12 + a2) * 6 + a];
    float m = la[0];
#pragma unroll
    for (int a = 1; a < NUM_ACT; a++) m = fmaxf(m, la[a]);
    float e[NUM_ACT], Z = 0.f;
#pragma unroll
    for (int a = 0; a < NUM_ACT; a++) { e[a] = expf(la[a] - m); Z += e[a]; }
    float wz = (p1a / tot) / Z;
#pragma unroll
    for (int a = 0; a < NUM_ACT; a++) o[a] = wz * e[a];
  }
  if (hasb) {
    float la[NUM_ACT];
#pragma unroll
    for (int a = 0; a < NUM_ACT; a++)
      la[a] = xw[a] + L[ab0 * 6 + a] + L[(6 + ab1) * 6 + a] + L[(12 + ab2) * 6 + a];
    float m = la[0];
#pragma unroll
    for (int a = 1; a < NUM_ACT; a++) m = fmaxf(m, la[a]);
    float e[NUM_ACT], Z = 0.f;
#pragma unroll
    for (int a = 0; a < NUM_ACT; a++) { e[a] = expf(la[a] - m); Z += e[a]; }
    float wz = (p1b / tot) / Z;
#pragma unroll
    for (int a = 0; a < NUM_ACT; a++) o[a] += wz * e[a];
  }
#pragma unroll
  for (int m = 32; m > 0; m >>= 1)
#pragma unroll
    for (int a = 0; a < NUM_ACT; a++) o[a] += __shfl_xor(o[a], m);

  // fire-and-forget outputs (no barrier after any of these)
  if (l == 0) {
#pragma unroll
    for (int a = 0; a < NUM_ACT; a++) out[b * NUM_ACT + a] = o[a];
    ws_H[b] = H;
  }
  if (l < 18) {
    int k = l / 6, a = l - k * 6;
    out[BATCH * NUM_ACT + ((size_t)k * BATCH + b) * NUM_ACT + a] = L[112 + l];
  }
}

// ---------------- Entropy reduce: 4096 floats -> 1 scalar (verified R2) ----
__global__ __launch_bounds__(256) void k_ent(const float* __restrict__ ws_H,
                                             float* __restrict__ out) {
  const int t = threadIdx.x;
  const float4* p = (const float4*)ws_H;
  float s = 0.f;
#pragma unroll
  for (int i = 0; i < 4; i++) {
    float4 v = p[t + 256 * i];
    s += v.x + v.y + v.z + v.w;
  }
#pragma unroll
  for (int m = 32; m > 0; m >>= 1) s += __shfl_xor(s, m);
  __shared__ float sw[4];
  if ((t & 63) == 0) sw[t >> 6] = s;
  __syncthreads();
  if (t == 0)
    out[ENT_IDX] = (sw[0] + sw[1] + sw[2] + sw[3]) * (1.0f / 12288.0f);
}

extern "C" void kernel_launch(void* const* d_in, const int* in_sizes, int n_in,
                              void* d_out, int out_size, void* d_ws, size_t ws_size,
                              hipStream_t stream) {
  const float* x    = (const float*)d_in[0];
  const float* Wopp = (const float*)d_in[1];
  const float* bopp = (const float*)d_in[2];
  const float* W    = (const float*)d_in[3];
  const float* bias = (const float*)d_in[4];
  float* out = (float*)d_out;
  float* part = (float*)d_ws;

  size_t need8 = ((size_t)8 * ACC_STRIDE + BATCH) * sizeof(float);
  if (ws_size >= need8) {
    float* ws_H = part + (size_t)8 * ACC_STRIDE;
    k1_gemm<8><<<(BATCH / TROWS) * 8, 128, 0, stream>>>(x, Wopp, W, part);
    k3f<8><<<BATCH / 4, 256, 0, stream>>>(part, bopp, W, bias, out, ws_H);
    k_ent<<<1, 256, 0, stream>>>(ws_H, out);
  } else {
    float* ws_H = part + (size_t)4 * ACC_STRIDE;
    k1_gemm<4><<<(BATCH / TROWS) * 4, 128, 0, stream>>>(x, Wopp, W, part);
    k3f<4><<<BATCH / 4, 256, 0, stream>>>(part, bopp, W, bias, out, ws_H);
    k_ent<<<1, 256, 0, stream>>>(ws_H, out);
  }
}

// Round 4
// 83.123 us; speedup vs baseline: 1.6018x; 1.0430x over previous
//
#include <hip/hip_runtime.h>
#include <stdint.h>

#define NUM_ACT 6
#define NUM_OPP 3
#define NUM_SAMPLE 80
#define BATCH 4096
#define DIM 512
#define ACC_STRIDE 98304   /* BATCH*24 */
#define TROWS 32
#define ENT_IDX 98304      /* BATCH*6 + 3*BATCH*6 */

// ---------------- JAX threefry2x32 (key = (0, 42)) ----------------
__device__ __forceinline__ uint32_t rotl32(uint32_t x, int d) {
  return (x << d) | (x >> (32 - d));
}

__device__ __forceinline__ void tf_round4(uint32_t& x0, uint32_t& x1,
                                          int r0, int r1, int r2, int r3) {
  x0 += x1; x1 = rotl32(x1, r0); x1 ^= x0;
  x0 += x1; x1 = rotl32(x1, r1); x1 ^= x0;
  x0 += x1; x1 = rotl32(x1, r2); x1 ^= x0;
  x0 += x1; x1 = rotl32(x1, r3); x1 ^= x0;
}

__device__ __forceinline__ void threefry2x32(uint32_t k0, uint32_t k1,
                                             uint32_t& x0, uint32_t& x1) {
  const uint32_t ks2 = k0 ^ k1 ^ 0x1BD11BDAu;
  x0 += k0;  x1 += k1;
  tf_round4(x0, x1, 13, 15, 26, 6);  x0 += k1;  x1 += ks2 + 1u;
  tf_round4(x0, x1, 17, 29, 16, 24); x0 += ks2; x1 += k0  + 2u;
  tf_round4(x0, x1, 13, 15, 26, 6);  x0 += k0;  x1 += k1  + 3u;
  tf_round4(x0, x1, 17, 29, 16, 24); x0 += k1;  x1 += ks2 + 4u;
  tf_round4(x0, x1, 13, 15, 26, 6);  x0 += ks2; x1 += k0  + 5u;
}

__device__ __forceinline__ float jax_uniform(uint32_t flat_idx) {
  uint32_t x0 = 0u, x1 = flat_idx;
  threefry2x32(0u, 42u, x0, x1);
  uint32_t bits = x0 ^ x1;
  return __uint_as_float((bits >> 9) | 0x3f800000u) - 1.0f;   // [0,1)
}

__device__ __forceinline__ void dot4(float& a, float4 u, float4 v) {
  a = fmaf(u.x, v.x, a); a = fmaf(u.y, v.y, a);
  a = fmaf(u.z, v.z, a); a = fmaf(u.w, v.w, a);
}

// ---------------- K1: split-K tiled GEMM -> per-chunk partials ----------------
// VERBATIM from the verified R0 kernel (defines logit bit patterns).
// Only addition: block 0 zeroes out[ENT_IDX] (kernel-boundary visible to k3f).
template<int NCH>
__global__ __launch_bounds__(128) void k1_gemm(
    const float* __restrict__ x, const float* __restrict__ Wopp,
    const float* __restrict__ W, float* __restrict__ part,
    float* __restrict__ out) {
  constexpr int WIDTH = 512 / NCH;
  constexpr int XSTR = WIDTH + 4;
  const int tile = blockIdx.x / NCH;
  const int ch = blockIdx.x % NCH;
  const int rowbase = tile * TROWS;
  const int dbase = ch * WIDTH;
  __shared__ float xs[TROWS * XSTR];
  __shared__ float wt[24 * XSTR];
  const int t = threadIdx.x;

  for (int f = t; f < TROWS * (WIDTH / 4); f += 128) {
    int row = f / (WIDTH / 4), c4 = (f % (WIDTH / 4)) << 2;
    float4 v = *(const float4*)(x + (size_t)(rowbase + row) * DIM + dbase + c4);
    *(float4*)(xs + row * XSTR + c4) = v;
  }
  for (int i = t; i < 24 * WIDTH; i += 128) {
    int c = i % 24, dd = i / 24;
    int d = dbase + dd;
    float v = (c < 18) ? Wopp[(c / 6) * (DIM * 6) + d * 6 + (c % 6)]
                       : W[d * 6 + (c - 18)];
    wt[c * XSTR + dd] = v;
  }
  __syncthreads();

  const int rowg = t >> 3, colg = t & 7;
  float acc[2][3] = {{0.f, 0.f, 0.f}, {0.f, 0.f, 0.f}};
  const float* xp = xs + (rowg * 2) * XSTR;
  const float* wp = wt + (colg * 3) * XSTR;
#pragma unroll 4
  for (int dd = 0; dd < WIDTH; dd += 4) {
    float4 x0 = *(const float4*)(xp + dd);
    float4 x1 = *(const float4*)(xp + XSTR + dd);
    float4 w0 = *(const float4*)(wp + dd);
    float4 w1 = *(const float4*)(wp + XSTR + dd);
    float4 w2 = *(const float4*)(wp + 2 * XSTR + dd);
    dot4(acc[0][0], x0, w0); dot4(acc[0][1], x0, w1); dot4(acc[0][2], x0, w2);
    dot4(acc[1][0], x1, w0); dot4(acc[1][1], x1, w1); dot4(acc[1][2], x1, w2);
  }
  const int r0 = rowbase + rowg * 2, c0 = colg * 3;
  float* p = part + (size_t)ch * ACC_STRIDE;
#pragma unroll
  for (int rr = 0; rr < 2; rr++)
#pragma unroll
    for (int cc = 0; cc < 3; cc++)
      p[(r0 + rr) * 24 + c0 + cc] = acc[rr][cc];
  if (blockIdx.x == 0 && t == 0) out[ENT_IDX] = 0.f;
}

// ---------------- K3f: wave-per-row tail, one barrier (LDS-only drain) -------
// 1024-thread blocks = 16 waves = 16 rows. Per-row math bit-identical to the
// verified R3 kernel. Partial-sum loads spread across 24 lanes (8 loads each,
// same bias-first g=0..7 fp sequence); softmax lanes gather via uniform shfl.
// Entropy: per-block LDS reduce + ONE atomicAdd (256 total, end-of-phase,
// fire-and-forget; barrier sits before any global stores -> free drain).
#define WSTR 144   /* per-wave LDS floats: [0,108) W2, [112,130) dist, [136,142) xw */

template<int NCH>
__global__ __launch_bounds__(1024) void k3f(
    const float* __restrict__ part, const float* __restrict__ bopp,
    const float* __restrict__ W, const float* __restrict__ bias,
    float* __restrict__ out) {
  const int w = threadIdx.x >> 6;
  const int l = threadIdx.x & 63;
  const int b = blockIdx.x * 16 + w;
  __shared__ float lds[16][WSTR];
  __shared__ float s_Hw[16];
  float* L = lds[w];

  // stage tail weights W2 (108 floats) into this wave's private strip
  if (l < 54) {
    float2 v = *(const float2*)(W + DIM * NUM_ACT + 2 * l);
    L[2 * l] = v.x; L[2 * l + 1] = v.y;
  }

  // ---- column sums: lane c<24 owns one logit column ----
  // fp sequence identical to verified R3: bias first, then chunks g=0..NCH-1.
  float colsum = 0.f;
  if (l < 24) {
    float s = (l < 18) ? bopp[l] : bias[l - 18];
#pragma unroll
    for (int g = 0; g < NCH; g++)
      s += part[g * ACC_STRIDE + b * 24 + l];
    colsum = s;
    if (l >= 18) L[136 + (l - 18)] = s;      // xw + bias (matches old path)
  }
  // uniform gather (all 64 lanes execute -> no divergent-shuffle UB)
  const int kk = (l < NUM_OPP) ? l : 0;
  float lg[NUM_ACT];
#pragma unroll
  for (int a = 0; a < NUM_ACT; a++)
    lg[a] = __shfl(colsum, kk * NUM_ACT + a);

  // ---- softmax per opponent on lanes 0..2 (identical fp sequence) ----
  float H = 0.f;
  if (l < NUM_OPP) {
    const int k = l;
    float m = lg[0];
#pragma unroll
    for (int a = 1; a < NUM_ACT; a++) m = fmaxf(m, lg[a]);
    float e[NUM_ACT], Z = 0.f;
#pragma unroll
    for (int a = 0; a < NUM_ACT; a++) { e[a] = expf(lg[a] - m); Z += e[a]; }
    float logZ = logf(Z);
#pragma unroll
    for (int a = 0; a < NUM_ACT; a++) {
      float pa = e[a] / Z;
      L[112 + k * NUM_ACT + a] = pa;
      H -= pa * ((lg[a] - m) - logZ);
    }
  }
  // gather H0+H1+H2 -> lane 0 (identical shfl sequence)
  H += __shfl_down(H, 1);
  H += __shfl_down(H, 2);
  if (l == 0) s_Hw[w] = H;

  // barrier BEFORE any global stores: drains only LDS/SMEM -> cheap.
  __syncthreads();
  if (threadIdx.x == 0) {
    float hs = 0.f;
#pragma unroll
    for (int i = 0; i < 16; i++) hs += s_Hw[i];
    atomicAdd(out + ENT_IDX, hs * (1.0f / 12288.0f));  // 256 total, one addr
  }

  // broadcast dist into registers
  float d[18];
#pragma unroll
  for (int i = 0; i < 18; i++) d[i] = L[112 + i];

  // ---- sampling: a-half (s = l) for k=0,1,2 on every lane ----
  int   act_a[3];
  float pr_a[3];
#pragma unroll
  for (int k = 0; k < NUM_OPP; k++) {
    float u = jax_uniform((uint32_t)(k * NUM_SAMPLE + l) * BATCH + (uint32_t)b);
    float c = d[k * 6 + 0], pr = d[k * 6 + 0];
    int sel = 0;
#pragma unroll
    for (int a = 1; a < NUM_ACT; a++) {
      bool take = (u >= c);
      sel += take ? 1 : 0;
      pr = take ? d[k * 6 + a] : pr;
      c += d[k * 6 + a];
    }
    act_a[k] = sel; pr_a[k] = pr;
  }
  // ---- b-half (s = 64 + l%16) computed on lanes 0..47, k = l/16 ----
  float prb = 0.f; int actb = 0;
  if (l < 48) {
    const int k = l >> 4, s = 64 + (l & 15);
    float u = jax_uniform((uint32_t)(k * NUM_SAMPLE + s) * BATCH + (uint32_t)b);
    float c = L[112 + k * 6 + 0], pr = c;
    int sel = 0;
#pragma unroll
    for (int a = 1; a < NUM_ACT; a++) {
      float da = L[112 + k * 6 + a];
      bool take = (u >= c);
      sel += take ? 1 : 0;
      pr = take ? da : pr;
      c += da;
    }
    actb = sel; prb = pr;
  }
  // redistribute b-half to lanes 0..15 (same sample->lane map: j = t+64)
  const int tm = l & 15;
  float pb0 = __shfl(prb, tm), pb1 = __shfl(prb, tm + 16), pb2 = __shfl(prb, tm + 32);
  int   ab0 = __shfl(actb, tm), ab1 = __shfl(actb, tm + 16), ab2 = __shfl(actb, tm + 32);

  const bool hasb = l < (NUM_SAMPLE - 64);
  float p1a = pr_a[0] * pr_a[1] * pr_a[2];
  float p1b = 0.f;
  if (hasb) p1b = pb0 * pb1 * pb2;
  float tot = p1a + p1b;
#pragma unroll
  for (int m = 32; m > 0; m >>= 1) tot += __shfl_xor(tot, m);

  float xw[NUM_ACT];
#pragma unroll
  for (int a = 0; a < NUM_ACT; a++) xw[a] = L[136 + a];

  float o[NUM_ACT];
#pragma unroll
  for (int a = 0; a < NUM_ACT; a++) o[a] = 0.f;
  {
    int a0 = act_a[0], a1 = act_a[1], a2 = act_a[2];
    float la[NUM_ACT];
#pragma unroll
    for (int a = 0; a < NUM_ACT; a++)
      la[a] = xw[a] + L[a0 * 6 + a] + L[(6 + a1) * 6 + a] + L[(12 + a2) * 6 + a];
    float m = la[0];
#pragma unroll
    for (int a = 1; a < NUM_ACT; a++) m = fmaxf(m, la[a]);
    float e[NUM_ACT], Z = 0.f;
#pragma unroll
    for (int a = 0; a < NUM_ACT; a++) { e[a] = expf(la[a] - m); Z += e[a]; }
    float wz = (p1a / tot) / Z;
#pragma unroll
    for (int a = 0; a < NUM_ACT; a++) o[a] = wz * e[a];
  }
  if (hasb) {
    float la[NUM_ACT];
#pragma unroll
    for (int a = 0; a < NUM_ACT; a++)
      la[a] = xw[a] + L[ab0 * 6 + a] + L[(6 + ab1) * 6 + a] + L[(12 + ab2) * 6 + a];
    float m = la[0];
#pragma unroll
    for (int a = 1; a < NUM_ACT; a++) m = fmaxf(m, la[a]);
    float e[NUM_ACT], Z = 0.f;
#pragma unroll
    for (int a = 0; a < NUM_ACT; a++) { e[a] = expf(la[a] - m); Z += e[a]; }
    float wz = (p1b / tot) / Z;
#pragma unroll
    for (int a = 0; a < NUM_ACT; a++) o[a] += wz * e[a];
  }
#pragma unroll
  for (int m = 32; m > 0; m >>= 1)
#pragma unroll
    for (int a = 0; a < NUM_ACT; a++) o[a] += __shfl_xor(o[a], m);

  // fire-and-forget outputs (no barrier after any of these)
  if (l == 0) {
#pragma unroll
    for (int a = 0; a < NUM_ACT; a++) out[b * NUM_ACT + a] = o[a];
  }
  if (l < 18) {
    int k = l / 6, a = l - k * 6;
    out[BATCH * NUM_ACT + ((size_t)k * BATCH + b) * NUM_ACT + a] = L[112 + l];
  }
}

extern "C" void kernel_launch(void* const* d_in, const int* in_sizes, int n_in,
                              void* d_out, int out_size, void* d_ws, size_t ws_size,
                              hipStream_t stream) {
  const float* x    = (const float*)d_in[0];
  const float* Wopp = (const float*)d_in[1];
  const float* bopp = (const float*)d_in[2];
  const float* W    = (const float*)d_in[3];
  const float* bias = (const float*)d_in[4];
  float* out = (float*)d_out;
  float* part = (float*)d_ws;

  size_t need8 = (size_t)8 * ACC_STRIDE * sizeof(float);
  if (ws_size >= need8) {
    k1_gemm<8><<<(BATCH / TROWS) * 8, 128, 0, stream>>>(x, Wopp, W, part, out);
    k3f<8><<<BATCH / 16, 1024, 0, stream>>>(part, bopp, W, bias, out);
  } else {
    k1_gemm<4><<<(BATCH / TROWS) * 4, 128, 0, stream>>>(x, Wopp, W, part, out);
    k3f<4><<<BATCH / 16, 1024, 0, stream>>>(part, bopp, W, bias, out);
  }
}

// Round 5
// 81.421 us; speedup vs baseline: 1.6353x; 1.0209x over previous
//
#include <hip/hip_runtime.h>
#include <stdint.h>

#define NUM_ACT 6
#define NUM_OPP 3
#define NUM_SAMPLE 80
#define BATCH 4096
#define DIM 512
#define ENT_IDX 98304      /* BATCH*6 + 3*BATCH*6 */

// ---------------- JAX threefry2x32 (key = (0, 42)) ----------------
__device__ __forceinline__ uint32_t rotl32(uint32_t x, int d) {
  return (x << d) | (x >> (32 - d));
}

__device__ __forceinline__ void tf_round4(uint32_t& x0, uint32_t& x1,
                                          int r0, int r1, int r2, int r3) {
  x0 += x1; x1 = rotl32(x1, r0); x1 ^= x0;
  x0 += x1; x1 = rotl32(x1, r1); x1 ^= x0;
  x0 += x1; x1 = rotl32(x1, r2); x1 ^= x0;
  x0 += x1; x1 = rotl32(x1, r3); x1 ^= x0;
}

__device__ __forceinline__ void threefry2x32(uint32_t k0, uint32_t k1,
                                             uint32_t& x0, uint32_t& x1) {
  const uint32_t ks2 = k0 ^ k1 ^ 0x1BD11BDAu;
  x0 += k0;  x1 += k1;
  tf_round4(x0, x1, 13, 15, 26, 6);  x0 += k1;  x1 += ks2 + 1u;
  tf_round4(x0, x1, 17, 29, 16, 24); x0 += ks2; x1 += k0  + 2u;
  tf_round4(x0, x1, 13, 15, 26, 6);  x0 += k0;  x1 += k1  + 3u;
  tf_round4(x0, x1, 17, 29, 16, 24); x0 += k1;  x1 += ks2 + 4u;
  tf_round4(x0, x1, 13, 15, 26, 6);  x0 += ks2; x1 += k0  + 5u;
}

__device__ __forceinline__ float jax_uniform(uint32_t flat_idx) {
  uint32_t x0 = 0u, x1 = flat_idx;
  threefry2x32(0u, 42u, x0, x1);
  uint32_t bits = x0 ^ x1;
  return __uint_as_float((bits >> 9) | 0x3f800000u) - 1.0f;   // [0,1)
}

__device__ __forceinline__ void dot4(float& a, float4 u, float4 v) {
  a = fmaf(u.x, v.x, a); a = fmaf(u.y, v.y, a);
  a = fmaf(u.z, v.z, a); a = fmaf(u.w, v.w, a);
}

// ---------------- LDS layout (floats), total 25340 -> ~99 KB static ----------
// XS  [8][16][68]  @ 0      : x tile, per-chunk rows (68 = 64+4 pad, 16B-mult)
// WT  [8][24][68]  @ 8704   : weight tile, [chunk][col][dd]
// PART[8][16][24]  @ 21760  : per-chunk partials (replaces global `part`)
// W2  [108]        @ 24832  : tail weights (shared by all waves)
// DIST[16][18]     @ 24940  : per-wave dist
// XW  [16][6]      @ 25228  : per-wave xw+bias
// HW  [16]         @ 25324  : per-wave entropy
#define O_XS   0
#define O_WT   8704
#define O_PART 21760
#define O_W2   24832
#define O_DIST 24940
#define O_XW   25228
#define O_HW   25324

// ---------------- Single kernel: GEMM (LDS partials) + tail ----------------
// Phase 1 reproduces k1<8>'s per-accumulator fp sequence exactly (each
// (row, col) dot is the same serial dot4 chain over dd=0..63 on the same
// values; 1-row thread units vs 2-row changes only WHO computes, not bits).
// Phase 2 is the verified R4 tail verbatim, reading partials from LDS.
__global__ __launch_bounds__(1024) void k_all(
    const float* __restrict__ x, const float* __restrict__ Wopp,
    const float* __restrict__ bopp, const float* __restrict__ W,
    const float* __restrict__ bias, float* __restrict__ out) {
  __shared__ float sm[25340];
  const int t = threadIdx.x;
  const int w = t >> 6;            // wave = row within tile
  const int l = t & 63;
  const int rowbase = blockIdx.x * 16;
  const int b = rowbase + w;

  // ---- Phase A: stage x tile (float4, full-row coalesced), weights, W2 ----
  for (int u = t; u < 16 * 128; u += 1024) {           // 2048 float4 = 32 KB
    int row = u >> 7, c4 = (u & 127) << 2;             // d = c4 in [0,512)
    float4 v = *(const float4*)(x + (size_t)(rowbase + row) * DIM + c4);
    *(float4*)(sm + O_XS + (c4 >> 6) * 1088 + row * 68 + (c4 & 63)) = v;
  }
  for (int i = t; i < 24 * 512; i += 1024) {           // same values as k1's wt
    int d = i / 24, c = i % 24;
    float v = (c < 18) ? Wopp[(c / 6) * (DIM * 6) + d * 6 + (c % 6)]
                       : W[d * 6 + (c - 18)];
    sm[O_WT + (d >> 6) * 1632 + c * 68 + (d & 63)] = v;
  }
  if (t < 54) {
    float2 v = *(const float2*)(W + DIM * NUM_ACT + 2 * t);
    sm[O_W2 + 2 * t] = v.x; sm[O_W2 + 2 * t + 1] = v.y;
  }
  __syncthreads();

  // ---- Phase B: GEMM. thread = (chunk sub, row, col-triple) ----
  {
    const int sub = t >> 7, tt = t & 127;
    const int row = tt >> 3, colg = tt & 7;
    const float* xp = sm + O_XS + sub * 1088 + row * 68;
    const float* wp = sm + O_WT + sub * 1632 + (colg * 3) * 68;
    float a0 = 0.f, a1 = 0.f, a2 = 0.f;
#pragma unroll 4
    for (int dd = 0; dd < 64; dd += 4) {
      float4 xv = *(const float4*)(xp + dd);
      dot4(a0, xv, *(const float4*)(wp + dd));
      dot4(a1, xv, *(const float4*)(wp + 68 + dd));
      dot4(a2, xv, *(const float4*)(wp + 136 + dd));
    }
    float* pp = sm + O_PART + sub * 384 + row * 24 + colg * 3;
    pp[0] = a0; pp[1] = a1; pp[2] = a2;
  }
  __syncthreads();

  // ---- Phase C (R4 tail, verbatim; partials now from LDS) ----
  // column sums: lane c<24 owns one logit column; bias first, g=0..7.
  float colsum = 0.f;
  if (l < 24) {
    float s = (l < 18) ? bopp[l] : bias[l - 18];
#pragma unroll
    for (int g = 0; g < 8; g++)
      s += sm[O_PART + g * 384 + w * 24 + l];
    colsum = s;
    if (l >= 18) sm[O_XW + w * 6 + (l - 18)] = s;
  }
  // uniform gather (all 64 lanes execute -> no divergent-shuffle UB)
  const int kk = (l < NUM_OPP) ? l : 0;
  float lg[NUM_ACT];
#pragma unroll
  for (int a = 0; a < NUM_ACT; a++)
    lg[a] = __shfl(colsum, kk * NUM_ACT + a);

  // softmax per opponent on lanes 0..2 (identical fp sequence)
  float H = 0.f;
  if (l < NUM_OPP) {
    const int k = l;
    float m = lg[0];
#pragma unroll
    for (int a = 1; a < NUM_ACT; a++) m = fmaxf(m, lg[a]);
    float e[NUM_ACT], Z = 0.f;
#pragma unroll
    for (int a = 0; a < NUM_ACT; a++) { e[a] = expf(lg[a] - m); Z += e[a]; }
    float logZ = logf(Z);
#pragma unroll
    for (int a = 0; a < NUM_ACT; a++) {
      float pa = e[a] / Z;
      sm[O_DIST + w * 18 + k * NUM_ACT + a] = pa;
      H -= pa * ((lg[a] - m) - logZ);
    }
  }
  // gather H0+H1+H2 -> lane 0 (identical shfl sequence)
  H += __shfl_down(H, 1);
  H += __shfl_down(H, 2);
  if (l == 0) sm[O_HW + w] = H;

  // barrier for s_Hw only (no outstanding global stores -> cheap drain)
  __syncthreads();
  if (t == 0) {
    float hs = 0.f;
#pragma unroll
    for (int i = 0; i < 16; i++) hs += sm[O_HW + i];
    atomicAdd(out + ENT_IDX, hs * (1.0f / 12288.0f));  // 256 total, one addr
  }

  // broadcast dist into registers (in-wave DS ordering; no barrier needed)
  float d[18];
#pragma unroll
  for (int i = 0; i < 18; i++) d[i] = sm[O_DIST + w * 18 + i];

  // sampling: a-half (s = l) for k=0,1,2 on every lane
  int   act_a[3];
  float pr_a[3];
#pragma unroll
  for (int k = 0; k < NUM_OPP; k++) {
    float u = jax_uniform((uint32_t)(k * NUM_SAMPLE + l) * BATCH + (uint32_t)b);
    float c = d[k * 6 + 0], pr = d[k * 6 + 0];
    int sel = 0;
#pragma unroll
    for (int a = 1; a < NUM_ACT; a++) {
      bool take = (u >= c);
      sel += take ? 1 : 0;
      pr = take ? d[k * 6 + a] : pr;
      c += d[k * 6 + a];
    }
    act_a[k] = sel; pr_a[k] = pr;
  }
  // b-half (s = 64 + l%16) computed on lanes 0..47, k = l/16
  float prb = 0.f; int actb = 0;
  if (l < 48) {
    const int k = l >> 4, s = 64 + (l & 15);
    float u = jax_uniform((uint32_t)(k * NUM_SAMPLE + s) * BATCH + (uint32_t)b);
    float c = sm[O_DIST + w * 18 + k * 6 + 0], pr = c;
    int sel = 0;
#pragma unroll
    for (int a = 1; a < NUM_ACT; a++) {
      float da = sm[O_DIST + w * 18 + k * 6 + a];
      bool take = (u >= c);
      sel += take ? 1 : 0;
      pr = take ? da : pr;
      c += da;
    }
    actb = sel; prb = pr;
  }
  // redistribute b-half to lanes 0..15 (same sample->lane map: j = t+64)
  const int tm = l & 15;
  float pb0 = __shfl(prb, tm), pb1 = __shfl(prb, tm + 16), pb2 = __shfl(prb, tm + 32);
  int   ab0 = __shfl(actb, tm), ab1 = __shfl(actb, tm + 16), ab2 = __shfl(actb, tm + 32);

  const bool hasb = l < (NUM_SAMPLE - 64);
  float p1a = pr_a[0] * pr_a[1] * pr_a[2];
  float p1b = 0.f;
  if (hasb) p1b = pb0 * pb1 * pb2;
  float tot = p1a + p1b;
#pragma unroll
  for (int m = 32; m > 0; m >>= 1) tot += __shfl_xor(tot, m);

  float xw[NUM_ACT];
#pragma unroll
  for (int a = 0; a < NUM_ACT; a++) xw[a] = sm[O_XW + w * 6 + a];

  float o[NUM_ACT];
#pragma unroll
  for (int a = 0; a < NUM_ACT; a++) o[a] = 0.f;
  {
    int a0 = act_a[0], a1 = act_a[1], a2 = act_a[2];
    float la[NUM_ACT];
#pragma unroll
    for (int a = 0; a < NUM_ACT; a++)
      la[a] = xw[a] + sm[O_W2 + a0 * 6 + a] + sm[O_W2 + (6 + a1) * 6 + a]
                    + sm[O_W2 + (12 + a2) * 6 + a];
    float m = la[0];
#pragma unroll
    for (int a = 1; a < NUM_ACT; a++) m = fmaxf(m, la[a]);
    float e[NUM_ACT], Z = 0.f;
#pragma unroll
    for (int a = 0; a < NUM_ACT; a++) { e[a] = expf(la[a] - m); Z += e[a]; }
    float wz = (p1a / tot) / Z;
#pragma unroll
    for (int a = 0; a < NUM_ACT; a++) o[a] = wz * e[a];
  }
  if (hasb) {
    float la[NUM_ACT];
#pragma unroll
    for (int a = 0; a < NUM_ACT; a++)
      la[a] = xw[a] + sm[O_W2 + ab0 * 6 + a] + sm[O_W2 + (6 + ab1) * 6 + a]
                    + sm[O_W2 + (12 + ab2) * 6 + a];
    float m = la[0];
#pragma unroll
    for (int a = 1; a < NUM_ACT; a++) m = fmaxf(m, la[a]);
    float e[NUM_ACT], Z = 0.f;
#pragma unroll
    for (int a = 0; a < NUM_ACT; a++) { e[a] = expf(la[a] - m); Z += e[a]; }
    float wz = (p1b / tot) / Z;
#pragma unroll
    for (int a = 0; a < NUM_ACT; a++) o[a] += wz * e[a];
  }
#pragma unroll
  for (int m = 32; m > 0; m >>= 1)
#pragma unroll
    for (int a = 0; a < NUM_ACT; a++) o[a] += __shfl_xor(o[a], m);

  // fire-and-forget outputs (no barrier after any of these)
  if (l == 0) {
#pragma unroll
    for (int a = 0; a < NUM_ACT; a++) out[b * NUM_ACT + a] = o[a];
  }
  if (l < 18) {
    int k = l / 6, a = l - k * 6;
    out[BATCH * NUM_ACT + ((size_t)k * BATCH + b) * NUM_ACT + a] =
        sm[O_DIST + w * 18 + l];
  }
}

extern "C" void kernel_launch(void* const* d_in, const int* in_sizes, int n_in,
                              void* d_out, int out_size, void* d_ws, size_t ws_size,
                              hipStream_t stream) {
  const float* x    = (const float*)d_in[0];
  const float* Wopp = (const float*)d_in[1];
  const float* bopp = (const float*)d_in[2];
  const float* W    = (const float*)d_in[3];
  const float* bias = (const float*)d_in[4];
  float* out = (float*)d_out;

  // zero the 4-byte entropy accumulator (stream-ordered, graph-capturable; R1)
  hipMemsetAsync(out + ENT_IDX, 0, sizeof(float), stream);
  k_all<<<BATCH / 16, 1024, 0, stream>>>(x, Wopp, bopp, W, bias, out);
}

// Round 6
// 81.403 us; speedup vs baseline: 1.6357x; 1.0002x over previous
//
#include <hip/hip_runtime.h>
#include <stdint.h>

#define NUM_ACT 6
#define NUM_OPP 3
#define NUM_SAMPLE 80
#define BATCH 4096
#define DIM 512
#define ENT_IDX 98304      /* BATCH*6 + 3*BATCH*6 */

// ---------------- JAX threefry2x32 (key = (0, 42)) ----------------
__device__ __forceinline__ uint32_t rotl32(uint32_t x, int d) {
  return (x << d) | (x >> (32 - d));
}

__device__ __forceinline__ void tf_round4(uint32_t& x0, uint32_t& x1,
                                          int r0, int r1, int r2, int r3) {
  x0 += x1; x1 = rotl32(x1, r0); x1 ^= x0;
  x0 += x1; x1 = rotl32(x1, r1); x1 ^= x0;
  x0 += x1; x1 = rotl32(x1, r2); x1 ^= x0;
  x0 += x1; x1 = rotl32(x1, r3); x1 ^= x0;
}

__device__ __forceinline__ void threefry2x32(uint32_t k0, uint32_t k1,
                                             uint32_t& x0, uint32_t& x1) {
  const uint32_t ks2 = k0 ^ k1 ^ 0x1BD11BDAu;
  x0 += k0;  x1 += k1;
  tf_round4(x0, x1, 13, 15, 26, 6);  x0 += k1;  x1 += ks2 + 1u;
  tf_round4(x0, x1, 17, 29, 16, 24); x0 += ks2; x1 += k0  + 2u;
  tf_round4(x0, x1, 13, 15, 26, 6);  x0 += k0;  x1 += k1  + 3u;
  tf_round4(x0, x1, 17, 29, 16, 24); x0 += k1;  x1 += ks2 + 4u;
  tf_round4(x0, x1, 13, 15, 26, 6);  x0 += ks2; x1 += k0  + 5u;
}

__device__ __forceinline__ float jax_uniform(uint32_t flat_idx) {
  uint32_t x0 = 0u, x1 = flat_idx;
  threefry2x32(0u, 42u, x0, x1);
  uint32_t bits = x0 ^ x1;
  return __uint_as_float((bits >> 9) | 0x3f800000u) - 1.0f;   // [0,1)
}

__device__ __forceinline__ void dot4(float& a, float4 u, float4 v) {
  a = fmaf(u.x, v.x, a); a = fmaf(u.y, v.y, a);
  a = fmaf(u.z, v.z, a); a = fmaf(u.w, v.w, a);
}

// ---------------- LDS layout (floats), total 19252 -> ~75 KB (2 blocks/CU) --
// XS  [8][8][68]   @ 0      : x tile  [chunk][row][dd] (68 = 64+4 pad)
// WT  [8][24][68]  @ 4352   : weights [chunk][col][dd]
// PART[8][8][24]   @ 17408  : per-chunk partials
// W2  [108]        @ 18944  : tail weights
// DIST[8][18]      @ 19052  : per-wave dist
// XW  [8][6]       @ 19196  : per-wave xw+bias
// HW  [8]          @ 19244  : per-wave entropy
#define O_XS   0
#define O_WT   4352
#define O_PART 17408
#define O_W2   18944
#define O_DIST 19052
#define O_XW   19196
#define O_HW   19244

// ---------------- Single kernel: 8 rows/block, 512 thr, 2 blocks/CU ---------
// All fp sequences bit-identical to the verified R5 kernel: same per-(row,col)
// serial dot4 chains over each 64-chunk, same bias-first g=0..7 column sums,
// same softmax / threefry / CDF / tail code. Only the work DISTRIBUTION and
// the weight staging access pattern changed (coalesced float4 + LDS scatter).
__global__ __launch_bounds__(512) void k_all(
    const float* __restrict__ x, const float* __restrict__ Wopp,
    const float* __restrict__ bopp, const float* __restrict__ W,
    const float* __restrict__ bias, float* __restrict__ out) {
  __shared__ float sm[19252];
  const int t = threadIdx.x;
  const int w = t >> 6;            // wave = row within tile (phase C)
  const int l = t & 63;
  const int rowbase = blockIdx.x * 8;
  const int b = rowbase + w;

  // ---- Phase A: stage x tile (coalesced float4) ----
  for (int u = t; u < 8 * 128; u += 512) {             // 1024 float4 = 16 KB
    int row = u >> 7, c4 = (u & 127) << 2;             // d = c4 in [0,512)
    float4 v = *(const float4*)(x + (size_t)(rowbase + row) * DIM + c4);
    *(float4*)(sm + O_XS + (c4 >> 6) * 544 + row * 68 + (c4 & 63)) = v;
  }
  // ---- weights: coalesced float4 linear load + LDS transpose-scatter ----
  // Wopp flat [0,9216): k=f/3072, d=(f%3072)/6, a=f%6 -> c=k*6+a
  // W    flat [0,3072): d=f/6, a=f%6              -> c=18+a
  for (int j = t; j < 3072; j += 512) {                // 6 iters/thread
    int f = j << 2;
    float4 v = (f < 9216) ? *(const float4*)(Wopp + f)
                          : *(const float4*)(W + (f - 9216));
    float vv[4] = {v.x, v.y, v.z, v.w};
#pragma unroll
    for (int e = 0; e < 4; e++) {
      int ff = f + e;
      int c, d;
      if (ff < 9216) { int k = ff / 3072, r = ff % 3072; d = r / 6; c = k * 6 + r % 6; }
      else           { int r = ff - 9216; d = r / 6; c = 18 + r % 6; }
      sm[O_WT + (d >> 6) * 1632 + c * 68 + (d & 63)] = vv[e];
    }
  }
  if (t < 54) {
    float2 v = *(const float2*)(W + DIM * NUM_ACT + 2 * t);
    sm[O_W2 + 2 * t] = v.x; sm[O_W2 + 2 * t + 1] = v.y;
  }
  __syncthreads();

  // ---- Phase B: GEMM. thread = (chunk sub = wave, row, col-triple) ----
  {
    const int sub = t >> 6, row = (t >> 3) & 7, colg = t & 7;
    const float* xp = sm + O_XS + sub * 544 + row * 68;
    const float* wp = sm + O_WT + sub * 1632 + (colg * 3) * 68;
    float a0 = 0.f, a1 = 0.f, a2 = 0.f;
#pragma unroll 4
    for (int dd = 0; dd < 64; dd += 4) {
      float4 xv = *(const float4*)(xp + dd);
      dot4(a0, xv, *(const float4*)(wp + dd));
      dot4(a1, xv, *(const float4*)(wp + 68 + dd));
      dot4(a2, xv, *(const float4*)(wp + 136 + dd));
    }
    float* pp = sm + O_PART + sub * 192 + row * 24 + colg * 3;
    pp[0] = a0; pp[1] = a1; pp[2] = a2;
  }
  __syncthreads();

  // ---- Phase C (verified tail; partials from LDS) ----
  // column sums: lane c<24 owns one logit column; bias first, g=0..7.
  float colsum = 0.f;
  if (l < 24) {
    float s = (l < 18) ? bopp[l] : bias[l - 18];
#pragma unroll
    for (int g = 0; g < 8; g++)
      s += sm[O_PART + g * 192 + w * 24 + l];
    colsum = s;
    if (l >= 18) sm[O_XW + w * 6 + (l - 18)] = s;
  }
  // uniform gather (all 64 lanes execute -> no divergent-shuffle UB)
  const int kk = (l < NUM_OPP) ? l : 0;
  float lg[NUM_ACT];
#pragma unroll
  for (int a = 0; a < NUM_ACT; a++)
    lg[a] = __shfl(colsum, kk * NUM_ACT + a);

  // softmax per opponent on lanes 0..2 (identical fp sequence)
  float H = 0.f;
  if (l < NUM_OPP) {
    const int k = l;
    float m = lg[0];
#pragma unroll
    for (int a = 1; a < NUM_ACT; a++) m = fmaxf(m, lg[a]);
    float e[NUM_ACT], Z = 0.f;
#pragma unroll
    for (int a = 0; a < NUM_ACT; a++) { e[a] = expf(lg[a] - m); Z += e[a]; }
    float logZ = logf(Z);
#pragma unroll
    for (int a = 0; a < NUM_ACT; a++) {
      float pa = e[a] / Z;
      sm[O_DIST + w * 18 + k * NUM_ACT + a] = pa;
      H -= pa * ((lg[a] - m) - logZ);
    }
  }
  // gather H0+H1+H2 -> lane 0 (identical shfl sequence)
  H += __shfl_down(H, 1);
  H += __shfl_down(H, 2);
  if (l == 0) sm[O_HW + w] = H;

  // barrier for HW only (no outstanding global stores -> cheap drain)
  __syncthreads();
  if (t == 0) {
    float hs = 0.f;
#pragma unroll
    for (int i = 0; i < 8; i++) hs += sm[O_HW + i];
    atomicAdd(out + ENT_IDX, hs * (1.0f / 12288.0f));  // 512 total, one addr
  }

  // broadcast dist into registers (in-wave DS ordering; no barrier needed)
  float d[18];
#pragma unroll
  for (int i = 0; i < 18; i++) d[i] = sm[O_DIST + w * 18 + i];

  // sampling: a-half (s = l) for k=0,1,2 on every lane
  int   act_a[3];
  float pr_a[3];
#pragma unroll
  for (int k = 0; k < NUM_OPP; k++) {
    float u = jax_uniform((uint32_t)(k * NUM_SAMPLE + l) * BATCH + (uint32_t)b);
    float c = d[k * 6 + 0], pr = d[k * 6 + 0];
    int sel = 0;
#pragma unroll
    for (int a = 1; a < NUM_ACT; a++) {
      bool take = (u >= c);
      sel += take ? 1 : 0;
      pr = take ? d[k * 6 + a] : pr;
      c += d[k * 6 + a];
    }
    act_a[k] = sel; pr_a[k] = pr;
  }
  // b-half (s = 64 + l%16) computed on lanes 0..47, k = l/16
  float prb = 0.f; int actb = 0;
  if (l < 48) {
    const int k = l >> 4, s = 64 + (l & 15);
    float u = jax_uniform((uint32_t)(k * NUM_SAMPLE + s) * BATCH + (uint32_t)b);
    float c = sm[O_DIST + w * 18 + k * 6 + 0], pr = c;
    int sel = 0;
#pragma unroll
    for (int a = 1; a < NUM_ACT; a++) {
      float da = sm[O_DIST + w * 18 + k * 6 + a];
      bool take = (u >= c);
      sel += take ? 1 : 0;
      pr = take ? da : pr;
      c += da;
    }
    actb = sel; prb = pr;
  }
  // redistribute b-half to lanes 0..15 (same sample->lane map: j = t+64)
  const int tm = l & 15;
  float pb0 = __shfl(prb, tm), pb1 = __shfl(prb, tm + 16), pb2 = __shfl(prb, tm + 32);
  int   ab0 = __shfl(actb, tm), ab1 = __shfl(actb, tm + 16), ab2 = __shfl(actb, tm + 32);

  const bool hasb = l < (NUM_SAMPLE - 64);
  float p1a = pr_a[0] * pr_a[1] * pr_a[2];
  float p1b = 0.f;
  if (hasb) p1b = pb0 * pb1 * pb2;
  float tot = p1a + p1b;
#pragma unroll
  for (int m = 32; m > 0; m >>= 1) tot += __shfl_xor(tot, m);

  float xw[NUM_ACT];
#pragma unroll
  for (int a = 0; a < NUM_ACT; a++) xw[a] = sm[O_XW + w * 6 + a];

  float o[NUM_ACT];
#pragma unroll
  for (int a = 0; a < NUM_ACT; a++) o[a] = 0.f;
  {
    int a0 = act_a[0], a1 = act_a[1], a2 = act_a[2];
    float la[NUM_ACT];
#pragma unroll
    for (int a = 0; a < NUM_ACT; a++)
      la[a] = xw[a] + sm[O_W2 + a0 * 6 + a] + sm[O_W2 + (6 + a1) * 6 + a]
                    + sm[O_W2 + (12 + a2) * 6 + a];
    float m = la[0];
#pragma unroll
    for (int a = 1; a < NUM_ACT; a++) m = fmaxf(m, la[a]);
    float e[NUM_ACT], Z = 0.f;
#pragma unroll
    for (int a = 0; a < NUM_ACT; a++) { e[a] = expf(la[a] - m); Z += e[a]; }
    float wz = (p1a / tot) / Z;
#pragma unroll
    for (int a = 0; a < NUM_ACT; a++) o[a] = wz * e[a];
  }
  if (hasb) {
    float la[NUM_ACT];
#pragma unroll
    for (int a = 0; a < NUM_ACT; a++)
      la[a] = xw[a] + sm[O_W2 + ab0 * 6 + a] + sm[O_W2 + (6 + ab1) * 6 + a]
                    + sm[O_W2 + (12 + ab2) * 6 + a];
    float m = la[0];
#pragma unroll
    for (int a = 1; a < NUM_ACT; a++) m = fmaxf(m, la[a]);
    float e[NUM_ACT], Z = 0.f;
#pragma unroll
    for (int a = 0; a < NUM_ACT; a++) { e[a] = expf(la[a] - m); Z += e[a]; }
    float wz = (p1b / tot) / Z;
#pragma unroll
    for (int a = 0; a < NUM_ACT; a++) o[a] += wz * e[a];
  }
#pragma unroll
  for (int m = 32; m > 0; m >>= 1)
#pragma unroll
    for (int a = 0; a < NUM_ACT; a++) o[a] += __shfl_xor(o[a], m);

  // fire-and-forget outputs (no barrier after any of these)
  if (l == 0) {
#pragma unroll
    for (int a = 0; a < NUM_ACT; a++) out[b * NUM_ACT + a] = o[a];
  }
  if (l < 18) {
    int k = l / 6, a = l - k * 6;
    out[BATCH * NUM_ACT + ((size_t)k * BATCH + b) * NUM_ACT + a] =
        sm[O_DIST + w * 18 + l];
  }
}

extern "C" void kernel_launch(void* const* d_in, const int* in_sizes, int n_in,
                              void* d_out, int out_size, void* d_ws, size_t ws_size,
                              hipStream_t stream) {
  const float* x    = (const float*)d_in[0];
  const float* Wopp = (const float*)d_in[1];
  const float* bopp = (const float*)d_in[2];
  const float* W    = (const float*)d_in[3];
  const float* bias = (const float*)d_in[4];
  float* out = (float*)d_out;

  // zero the 4-byte entropy accumulator (stream-ordered, graph-capturable; R1)
  hipMemsetAsync(out + ENT_IDX, 0, sizeof(float), stream);
  k_all<<<BATCH / 8, 512, 0, stream>>>(x, Wopp, bopp, W, bias, out);
}